// Round 1
// baseline (1885.287 us; speedup 1.0000x reference)
//
#include <hip/hip_runtime.h>
#include <hip/hip_bf16.h>

#define N_NODES 50000
#define E_EDGES 800000
#define ETOT (E_EDGES + N_NODES)   // self-loops appended
#define IN_DIM 128
#define HID 64
#define HEADS 4
#define HC (HEADS * HID)           // 256
#define OUT_DIM 64
#define NEG_SLOPE 0.2f

// ---------------- GEMM: C[M,Nc] = A[M,K] @ B[K,Nc] (+bias) ----------------
// 64x64 tile per 256-thread block, 4x4 per thread, K-step 16.
__global__ __launch_bounds__(256) void gemm64(const float* __restrict__ A,
                                              const float* __restrict__ B,
                                              float* __restrict__ C,
                                              int M, int K, int Nc,
                                              const float* __restrict__ bias) {
    __shared__ float As[16][68];   // [kk][m], pad 68 -> float4 aligned, conflict-light
    __shared__ float Bs[16][68];   // [kk][n]
    const int t  = threadIdx.x;
    const int tx = t & 15, ty = t >> 4;
    const int m0 = blockIdx.x * 64, n0 = blockIdx.y * 64;

    float acc[4][4];
#pragma unroll
    for (int i = 0; i < 4; i++)
#pragma unroll
        for (int j = 0; j < 4; j++) acc[i][j] = 0.f;

    const int lk = t & 15;   // k within tile (A staging)
    const int lm = t >> 4;   // row base (A staging)
    const int bn = t & 63;   // col (B staging)
    const int bk = t >> 6;   // k base (B staging)

    for (int k0 = 0; k0 < K; k0 += 16) {
#pragma unroll
        for (int i = 0; i < 4; i++) {
            int m = lm + 16 * i;
            int gm = m0 + m;
            As[lk][m] = (gm < M) ? A[(long)gm * K + k0 + lk] : 0.f;
        }
#pragma unroll
        for (int i = 0; i < 4; i++) {
            int kk = bk + 4 * i;
            Bs[kk][bn] = B[(long)(k0 + kk) * Nc + n0 + bn];
        }
        __syncthreads();
#pragma unroll
        for (int kk = 0; kk < 16; kk++) {
            float4 a4 = *(const float4*)&As[kk][ty * 4];
            float4 b4 = *(const float4*)&Bs[kk][tx * 4];
            float av[4] = {a4.x, a4.y, a4.z, a4.w};
            float bv[4] = {b4.x, b4.y, b4.z, b4.w};
#pragma unroll
            for (int i = 0; i < 4; i++)
#pragma unroll
                for (int j = 0; j < 4; j++) acc[i][j] += av[i] * bv[j];
        }
        __syncthreads();
    }

#pragma unroll
    for (int i = 0; i < 4; i++) {
        int gm = m0 + ty * 4 + i;
        if (gm >= M) continue;
#pragma unroll
        for (int j = 0; j < 4; j++) {
            int gn = n0 + tx * 4 + j;
            float v = acc[i][j];
            if (bias) v += bias[gn];
            C[(long)gm * Nc + gn] = v;
        }
    }
}

// ---------------- per-node attention logits ----------------
// block = node; wave (64 lanes) = head; shuffle-reduce 64-wide dot
__global__ __launch_bounds__(256) void alphas_kernel(const float* __restrict__ xh,
                                                     const float* __restrict__ a_src,
                                                     const float* __restrict__ a_dst,
                                                     float* __restrict__ as_,
                                                     float* __restrict__ ad_) {
    int n = blockIdx.x;
    int h = threadIdx.x >> 6;
    int lane = threadIdx.x & 63;
    float v = xh[n * HC + h * HID + lane];
    float ps = v * a_src[h * HID + lane];
    float pd = v * a_dst[h * HID + lane];
#pragma unroll
    for (int off = 32; off; off >>= 1) {
        ps += __shfl_down(ps, off);
        pd += __shfl_down(pd, off);
    }
    if (lane == 0) {
        as_[n * HEADS + h] = ps;
        ad_[n * HEADS + h] = pd;
    }
}

// ---------------- edge pass 1: w = exp(leakyrelu(...)), denom += w ----------------
// softmax shift skipped: shift-invariant, |e| <~ 10 so exp() is safe in fp32.
__global__ __launch_bounds__(256) void edge_w_kernel(const int* __restrict__ ei,
                                                     const float* __restrict__ as_,
                                                     const float* __restrict__ ad_,
                                                     float* __restrict__ w,
                                                     float* __restrict__ denom) {
    long gid = (long)blockIdx.x * 256 + threadIdx.x;
    if (gid >= (long)ETOT * HEADS) return;
    int e = (int)(gid >> 2);
    int h = (int)(gid & 3);
    int s, d;
    if (e < E_EDGES) { s = ei[e]; d = ei[E_EDGES + e]; }
    else             { s = d = e - E_EDGES; }
    float el = as_[s * HEADS + h] + ad_[d * HEADS + h];
    float l  = el > 0.f ? el : NEG_SLOPE * el;
    float wv = __expf(l);
    w[gid] = wv;
    atomicAdd(&denom[d * HEADS + h], wv);
}

// ---------------- edge pass 2: out[dst] += (w/denom) * xh[src] ----------------
// block = edge, 256 threads = 256 channels
__global__ __launch_bounds__(256) void scatter_kernel(const int* __restrict__ ei,
                                                      const float* __restrict__ xh,
                                                      const float* __restrict__ w,
                                                      const float* __restrict__ denom,
                                                      float* __restrict__ out) {
    int e = blockIdx.x;
    int c = threadIdx.x;
    int h = c >> 6;
    int s, d;
    if (e < E_EDGES) { s = ei[e]; d = ei[E_EDGES + e]; }
    else             { s = d = e - E_EDGES; }
    float coeff = w[e * HEADS + h] / (denom[d * HEADS + h] + 1e-16f);
    atomicAdd(&out[d * HC + c], coeff * xh[s * HC + c]);
}

// ---------------- bias + relu ----------------
__global__ __launch_bounds__(256) void bias_relu_kernel(float* __restrict__ hbuf,
                                                        const float* __restrict__ b) {
    long gid = (long)blockIdx.x * 256 + threadIdx.x;
    if (gid >= (long)N_NODES * HC) return;
    hbuf[gid] = fmaxf(hbuf[gid] + b[gid & (HC - 1)], 0.f);
}

extern "C" void kernel_launch(void* const* d_in, const int* in_sizes, int n_in,
                              void* d_out, int out_size, void* d_ws, size_t ws_size,
                              hipStream_t stream) {
    const float* x   = (const float*)d_in[0];
    const int*   ei  = (const int*)d_in[1];
    // d_in[2] = edge_attr (ignored)
    const float* W1  = (const float*)d_in[3];
    const float* a_s1 = (const float*)d_in[4];
    const float* a_d1 = (const float*)d_in[5];
    const float* b1  = (const float*)d_in[6];
    const float* W2  = (const float*)d_in[7];
    const float* a_s2 = (const float*)d_in[8];
    const float* a_d2 = (const float*)d_in[9];
    const float* b2  = (const float*)d_in[10];
    const float* Wfc = (const float*)d_in[11];
    const float* bfc = (const float*)d_in[12];
    float* out = (float*)d_out;

    char* ws = (char*)d_ws;
    size_t off = 0;
    float* bufA  = (float*)(ws + off); off += (size_t)N_NODES * HC * 4;    // xh   (51.2MB)
    float* bufB  = (float*)(ws + off); off += (size_t)N_NODES * HC * 4;    // agg  (51.2MB)
    float* wbuf  = (float*)(ws + off); off += (size_t)ETOT * HEADS * 4;    // 13.6MB
    float* asb   = (float*)(ws + off); off += (size_t)N_NODES * HEADS * 4;
    float* adb   = (float*)(ws + off); off += (size_t)N_NODES * HEADS * 4;
    float* denom = (float*)(ws + off); off += (size_t)N_NODES * HEADS * 4;

    dim3 gemm_grid1((N_NODES + 63) / 64, HC / 64);
    dim3 gemm_grid_fc((N_NODES + 63) / 64, OUT_DIM / 64);
    int edge_w_blocks = (int)(((long)ETOT * HEADS + 255) / 256);
    int br_blocks = (int)(((long)N_NODES * HC + 255) / 256);

    // ---------- layer 1 ----------
    gemm64<<<gemm_grid1, 256, 0, stream>>>(x, W1, bufA, N_NODES, IN_DIM, HC, nullptr);
    alphas_kernel<<<N_NODES, 256, 0, stream>>>(bufA, a_s1, a_d1, asb, adb);
    hipMemsetAsync(denom, 0, (size_t)N_NODES * HEADS * 4, stream);
    hipMemsetAsync(bufB, 0, (size_t)N_NODES * HC * 4, stream);
    edge_w_kernel<<<edge_w_blocks, 256, 0, stream>>>(ei, asb, adb, wbuf, denom);
    scatter_kernel<<<ETOT, 256, 0, stream>>>(ei, bufA, wbuf, denom, bufB);
    bias_relu_kernel<<<br_blocks, 256, 0, stream>>>(bufB, b1);

    // ---------- layer 2 ----------
    gemm64<<<gemm_grid1, 256, 0, stream>>>(bufB, W2, bufA, N_NODES, HC, HC, nullptr);
    alphas_kernel<<<N_NODES, 256, 0, stream>>>(bufA, a_s2, a_d2, asb, adb);
    hipMemsetAsync(denom, 0, (size_t)N_NODES * HEADS * 4, stream);
    hipMemsetAsync(bufB, 0, (size_t)N_NODES * HC * 4, stream);
    edge_w_kernel<<<edge_w_blocks, 256, 0, stream>>>(ei, asb, adb, wbuf, denom);
    scatter_kernel<<<ETOT, 256, 0, stream>>>(ei, bufA, wbuf, denom, bufB);
    bias_relu_kernel<<<br_blocks, 256, 0, stream>>>(bufB, b2);

    // ---------- fc head ----------
    gemm64<<<gemm_grid_fc, 256, 0, stream>>>(bufB, Wfc, out, N_NODES, HC, OUT_DIM, bfc);
}

// Round 3
// 1066.131 us; speedup vs baseline: 1.7683x; 1.7683x over previous
//
#include <hip/hip_runtime.h>
#include <hip/hip_bf16.h>

#define N_NODES 50000
#define E_EDGES 800000
#define ETOT (E_EDGES + N_NODES)   // self-loops appended
#define IN_DIM 128
#define HID 64
#define HEADS 4
#define HC (HEADS * HID)           // 256
#define OUT_DIM 64
#define NEG_SLOPE 0.2f
#define SCAN_BLK 1024

// ---------------- GEMM: C[M,Nc] = A[M,K] @ B[K,Nc] (+bias) ----------------
__global__ __launch_bounds__(256) void gemm64(const float* __restrict__ A,
                                              const float* __restrict__ B,
                                              float* __restrict__ C,
                                              int M, int K, int Nc,
                                              const float* __restrict__ bias) {
    __shared__ float As[16][68];
    __shared__ float Bs[16][68];
    const int t  = threadIdx.x;
    const int tx = t & 15, ty = t >> 4;
    const int m0 = blockIdx.x * 64, n0 = blockIdx.y * 64;

    float acc[4][4];
#pragma unroll
    for (int i = 0; i < 4; i++)
#pragma unroll
        for (int j = 0; j < 4; j++) acc[i][j] = 0.f;

    const int lk = t & 15;
    const int lm = t >> 4;
    const int bn = t & 63;
    const int bk = t >> 6;

    for (int k0 = 0; k0 < K; k0 += 16) {
#pragma unroll
        for (int i = 0; i < 4; i++) {
            int m = lm + 16 * i;
            int gm = m0 + m;
            As[lk][m] = (gm < M) ? A[(long)gm * K + k0 + lk] : 0.f;
        }
#pragma unroll
        for (int i = 0; i < 4; i++) {
            int kk = bk + 4 * i;
            Bs[kk][bn] = B[(long)(k0 + kk) * Nc + n0 + bn];
        }
        __syncthreads();
#pragma unroll
        for (int kk = 0; kk < 16; kk++) {
            float4 a4 = *(const float4*)&As[kk][ty * 4];
            float4 b4 = *(const float4*)&Bs[kk][tx * 4];
            float av[4] = {a4.x, a4.y, a4.z, a4.w};
            float bv[4] = {b4.x, b4.y, b4.z, b4.w};
#pragma unroll
            for (int i = 0; i < 4; i++)
#pragma unroll
                for (int j = 0; j < 4; j++) acc[i][j] += av[i] * bv[j];
        }
        __syncthreads();
    }

#pragma unroll
    for (int i = 0; i < 4; i++) {
        int gm = m0 + ty * 4 + i;
        if (gm >= M) continue;
#pragma unroll
        for (int j = 0; j < 4; j++) {
            int gn = n0 + tx * 4 + j;
            float v = acc[i][j];
            if (bias) v += bias[gn];
            C[(long)gm * Nc + gn] = v;
        }
    }
}

// ---------------- per-node attention logits ----------------
__global__ __launch_bounds__(256) void alphas_kernel(const float* __restrict__ xh,
                                                     const float* __restrict__ a_src,
                                                     const float* __restrict__ a_dst,
                                                     float* __restrict__ as_,
                                                     float* __restrict__ ad_) {
    int n = blockIdx.x;
    int h = threadIdx.x >> 6;
    int lane = threadIdx.x & 63;
    float v = xh[n * HC + h * HID + lane];
    float ps = v * a_src[h * HID + lane];
    float pd = v * a_dst[h * HID + lane];
#pragma unroll
    for (int off = 32; off; off >>= 1) {
        ps += __shfl_down(ps, off);
        pd += __shfl_down(pd, off);
    }
    if (lane == 0) {
        as_[n * HEADS + h] = ps;
        ad_[n * HEADS + h] = pd;
    }
}

// ---------------- CSR build ----------------
__global__ __launch_bounds__(256) void hist_kernel(const int* __restrict__ ei,
                                                   int* __restrict__ deg) {
    int e = blockIdx.x * 256 + threadIdx.x;
    if (e >= ETOT) return;
    int d = (e < E_EDGES) ? ei[E_EDGES + e] : e - E_EDGES;
    atomicAdd(&deg[d], 1);
}

__global__ __launch_bounds__(SCAN_BLK) void scan_phase1(const int* __restrict__ deg,
                                                        int* __restrict__ rs,
                                                        int* __restrict__ partials,
                                                        int n) {
    __shared__ int tmp[SCAN_BLK];
    int i = blockIdx.x * SCAN_BLK + threadIdx.x;
    int v = (i < n) ? deg[i] : 0;
    tmp[threadIdx.x] = v;
    __syncthreads();
    for (int off = 1; off < SCAN_BLK; off <<= 1) {
        int t = (threadIdx.x >= (unsigned)off) ? tmp[threadIdx.x - off] : 0;
        __syncthreads();
        tmp[threadIdx.x] += t;
        __syncthreads();
    }
    if (i < n) rs[i] = tmp[threadIdx.x];
    if (threadIdx.x == SCAN_BLK - 1) partials[blockIdx.x] = tmp[SCAN_BLK - 1];
}

__global__ void scan_phase2(int* __restrict__ partials, int nb) {
    if (blockIdx.x == 0 && threadIdx.x == 0) {
        int s = 0;
        for (int i = 0; i < nb; i++) { s += partials[i]; partials[i] = s; }
    }
}

__global__ __launch_bounds__(SCAN_BLK) void scan_phase3(const int* __restrict__ deg,
                                                        int* __restrict__ rs,
                                                        const int* __restrict__ partials,
                                                        int n) {
    int i = blockIdx.x * SCAN_BLK + threadIdx.x;
    if (i < n) {
        int off = (blockIdx.x > 0) ? partials[blockIdx.x - 1] : 0;
        rs[i] = rs[i] + off - deg[i];
    } else if (i == n) {
        rs[n] = partials[gridDim.x - 1];
    }
}

__global__ __launch_bounds__(256) void fill_kernel(const int* __restrict__ ei,
                                                   int* __restrict__ cursor,
                                                   int* __restrict__ csr_eid) {
    int e = blockIdx.x * 256 + threadIdx.x;
    if (e >= ETOT) return;
    int d = (e < E_EDGES) ? ei[E_EDGES + e] : e - E_EDGES;
    int pos = atomicAdd(&cursor[d], 1);
    csr_eid[pos] = e;
}

// ---------------- CSR gather-aggregate, fused softmax+normalize+bias+relu ----------------
// block = dst node, 256 threads = 256 channels. denom computed in-loop
// (same edge set), so no atomics anywhere in the hot path.
__global__ __launch_bounds__(256) void agg_kernel(const int* __restrict__ ei,
                                                  const int* __restrict__ rs,
                                                  const int* __restrict__ csr_eid,
                                                  const float* __restrict__ xh,
                                                  const float* __restrict__ as_,
                                                  const float* __restrict__ ad_,
                                                  const float* __restrict__ bias,
                                                  float* __restrict__ out) {
    int n = blockIdx.x;
    int c = threadIdx.x;
    int h = c >> 6;
    int beg = rs[n], end = rs[n + 1];
    float adv = ad_[n * HEADS + h];
    float acc = 0.f;
    float wsum = 0.f;
    for (int p = beg; p < end; ++p) {
        int e = csr_eid[p];
        int s = (e < E_EDGES) ? ei[e] : e - E_EDGES;
        float l = as_[s * HEADS + h] + adv;
        l = l > 0.f ? l : NEG_SLOPE * l;
        float wv = __expf(l);
        wsum += wv;
        acc += wv * xh[(long)s * HC + c];
    }
    float v = acc / (wsum + 1e-16f) + bias[c];
    out[(long)n * HC + c] = fmaxf(v, 0.f);
}

extern "C" void kernel_launch(void* const* d_in, const int* in_sizes, int n_in,
                              void* d_out, int out_size, void* d_ws, size_t ws_size,
                              hipStream_t stream) {
    const float* x    = (const float*)d_in[0];
    const int*   ei   = (const int*)d_in[1];
    const float* W1   = (const float*)d_in[3];
    const float* a_s1 = (const float*)d_in[4];
    const float* a_d1 = (const float*)d_in[5];
    const float* b1   = (const float*)d_in[6];
    const float* W2   = (const float*)d_in[7];
    const float* a_s2 = (const float*)d_in[8];
    const float* a_d2 = (const float*)d_in[9];
    const float* b2   = (const float*)d_in[10];
    const float* Wfc  = (const float*)d_in[11];
    const float* bfc  = (const float*)d_in[12];
    float* out = (float*)d_out;

    char* ws = (char*)d_ws;
    size_t off = 0;
    float* bufA    = (float*)(ws + off); off += (size_t)N_NODES * HC * 4;      // xh
    float* bufB    = (float*)(ws + off); off += (size_t)N_NODES * HC * 4;      // agg out
    float* asb     = (float*)(ws + off); off += (size_t)N_NODES * HEADS * 4;
    float* adb     = (float*)(ws + off); off += (size_t)N_NODES * HEADS * 4;
    int*   deg     = (int*)(ws + off);   off += (size_t)N_NODES * 4;
    int*   rs      = (int*)(ws + off);   off += (size_t)(N_NODES + 1) * 4;
    int*   cursor  = (int*)(ws + off);   off += (size_t)N_NODES * 4;
    int*   partials= (int*)(ws + off);   off += 256 * 4;
    int*   csr_eid = (int*)(ws + off);   off += (size_t)ETOT * 4;

    dim3 gemm_grid1((N_NODES + 63) / 64, HC / 64);
    dim3 gemm_grid_fc((N_NODES + 63) / 64, OUT_DIM / 64);
    int edge_blocks  = (ETOT + 255) / 256;
    int scan_blocks  = (N_NODES + SCAN_BLK - 1) / SCAN_BLK;
    int scan_blocks3 = (N_NODES + 1 + SCAN_BLK - 1) / SCAN_BLK;

    // ---------- CSR build (shared by both layers) ----------
    hipMemsetAsync(deg, 0, (size_t)N_NODES * 4, stream);
    hist_kernel<<<edge_blocks, 256, 0, stream>>>(ei, deg);
    scan_phase1<<<scan_blocks, SCAN_BLK, 0, stream>>>(deg, rs, partials, N_NODES);
    scan_phase2<<<1, 64, 0, stream>>>(partials, scan_blocks);
    scan_phase3<<<scan_blocks3, SCAN_BLK, 0, stream>>>(deg, rs, partials, N_NODES);
    hipMemcpyAsync(cursor, rs, (size_t)N_NODES * 4, hipMemcpyDeviceToDevice, stream);
    fill_kernel<<<edge_blocks, 256, 0, stream>>>(ei, cursor, csr_eid);

    // ---------- layer 1 ----------
    gemm64<<<gemm_grid1, 256, 0, stream>>>(x, W1, bufA, N_NODES, IN_DIM, HC, nullptr);
    alphas_kernel<<<N_NODES, 256, 0, stream>>>(bufA, a_s1, a_d1, asb, adb);
    agg_kernel<<<N_NODES, 256, 0, stream>>>(ei, rs, csr_eid, bufA, asb, adb, b1, bufB);

    // ---------- layer 2 ----------
    gemm64<<<gemm_grid1, 256, 0, stream>>>(bufB, W2, bufA, N_NODES, HC, HC, nullptr);
    alphas_kernel<<<N_NODES, 256, 0, stream>>>(bufA, a_s2, a_d2, asb, adb);
    agg_kernel<<<N_NODES, 256, 0, stream>>>(ei, rs, csr_eid, bufA, asb, adb, b2, bufB);

    // ---------- fc head ----------
    gemm64<<<gemm_grid_fc, 256, 0, stream>>>(bufB, Wfc, out, N_NODES, HC, OUT_DIM, bfc);
}

// Round 4
// 548.376 us; speedup vs baseline: 3.4379x; 1.9442x over previous
//
#include <hip/hip_runtime.h>
#include <hip/hip_bf16.h>

#define N_NODES 50000
#define E_EDGES 800000
#define ETOT (E_EDGES + N_NODES)   // self-loops appended
#define IN_DIM 128
#define HID 64
#define HEADS 4
#define HC (HEADS * HID)           // 256
#define OUT_DIM 64
#define NEG_SLOPE 0.2f
#define SCAN_BLK 1024

// ---------------- GEMM + fused alpha: xh(bf16) = A @ W ; as_/ad_ = xh . a ----------------
// 64x64 tile, 256 threads, 4x4/thread. Each tile's 64 columns = one full head,
// so per-row alpha dots are computed exactly (fp32 accumulators) in-epilogue.
__global__ __launch_bounds__(256) void gemm_xh(const float* __restrict__ A,
                                               const float* __restrict__ B,
                                               __hip_bfloat16* __restrict__ Cb,
                                               int M, int K,
                                               const float* __restrict__ a_src,
                                               const float* __restrict__ a_dst,
                                               float* __restrict__ as_,
                                               float* __restrict__ ad_) {
    const int Nc = HC;
    __shared__ float As[16][68];
    __shared__ float Bs[16][68];
    const int t  = threadIdx.x;
    const int tx = t & 15, ty = t >> 4;
    const int m0 = blockIdx.x * 64, n0 = blockIdx.y * 64;
    const int head = blockIdx.y;   // 64 cols per head

    float acc[4][4];
#pragma unroll
    for (int i = 0; i < 4; i++)
#pragma unroll
        for (int j = 0; j < 4; j++) acc[i][j] = 0.f;

    const int lk = t & 15;
    const int lm = t >> 4;
    const int bn = t & 63;
    const int bk = t >> 6;

    for (int k0 = 0; k0 < K; k0 += 16) {
#pragma unroll
        for (int i = 0; i < 4; i++) {
            int m = lm + 16 * i;
            int gm = m0 + m;
            As[lk][m] = (gm < M) ? A[(long)gm * K + k0 + lk] : 0.f;
        }
#pragma unroll
        for (int i = 0; i < 4; i++) {
            int kk = bk + 4 * i;
            Bs[kk][bn] = B[(long)(k0 + kk) * Nc + n0 + bn];
        }
        __syncthreads();
#pragma unroll
        for (int kk = 0; kk < 16; kk++) {
            float4 a4 = *(const float4*)&As[kk][ty * 4];
            float4 b4 = *(const float4*)&Bs[kk][tx * 4];
            float av[4] = {a4.x, a4.y, a4.z, a4.w};
            float bv[4] = {b4.x, b4.y, b4.z, b4.w};
#pragma unroll
            for (int i = 0; i < 4; i++)
#pragma unroll
                for (int j = 0; j < 4; j++) acc[i][j] += av[i] * bv[j];
        }
        __syncthreads();
    }

    // epilogue: bf16 store + per-row alpha dots reduced over the 16 tx lanes
    float asv[4];  // a_src coefficients for this thread's 4 columns
    float adv[4];
#pragma unroll
    for (int j = 0; j < 4; j++) {
        asv[j] = a_src[head * HID + tx * 4 + j];
        adv[j] = a_dst[head * HID + tx * 4 + j];
    }
#pragma unroll
    for (int i = 0; i < 4; i++) {
        int gm = m0 + ty * 4 + i;
        float ps = 0.f, pd = 0.f;
#pragma unroll
        for (int j = 0; j < 4; j++) {
            float v = acc[i][j];
            ps += v * asv[j];
            pd += v * adv[j];
        }
        // reduce across 16 consecutive lanes (same ty)
#pragma unroll
        for (int off = 8; off; off >>= 1) {
            ps += __shfl_down(ps, off);
            pd += __shfl_down(pd, off);
        }
        if (gm < M) {
#pragma unroll
            for (int j = 0; j < 4; j++) {
                int gn = n0 + tx * 4 + j;
                Cb[(long)gm * Nc + gn] = __float2bfloat16(acc[i][j]);
            }
            if (tx == 0) {
                as_[gm * HEADS + head] = ps;
                ad_[gm * HEADS + head] = pd;
            }
        }
    }
}

// ---------------- plain fp32 GEMM (+bias) for the FC head ----------------
__global__ __launch_bounds__(256) void gemm64(const float* __restrict__ A,
                                              const float* __restrict__ B,
                                              float* __restrict__ C,
                                              int M, int K, int Nc,
                                              const float* __restrict__ bias) {
    __shared__ float As[16][68];
    __shared__ float Bs[16][68];
    const int t  = threadIdx.x;
    const int tx = t & 15, ty = t >> 4;
    const int m0 = blockIdx.x * 64, n0 = blockIdx.y * 64;

    float acc[4][4];
#pragma unroll
    for (int i = 0; i < 4; i++)
#pragma unroll
        for (int j = 0; j < 4; j++) acc[i][j] = 0.f;

    const int lk = t & 15;
    const int lm = t >> 4;
    const int bn = t & 63;
    const int bk = t >> 6;

    for (int k0 = 0; k0 < K; k0 += 16) {
#pragma unroll
        for (int i = 0; i < 4; i++) {
            int m = lm + 16 * i;
            int gm = m0 + m;
            As[lk][m] = (gm < M) ? A[(long)gm * K + k0 + lk] : 0.f;
        }
#pragma unroll
        for (int i = 0; i < 4; i++) {
            int kk = bk + 4 * i;
            Bs[kk][bn] = B[(long)(k0 + kk) * Nc + n0 + bn];
        }
        __syncthreads();
#pragma unroll
        for (int kk = 0; kk < 16; kk++) {
            float4 a4 = *(const float4*)&As[kk][ty * 4];
            float4 b4 = *(const float4*)&Bs[kk][tx * 4];
            float av[4] = {a4.x, a4.y, a4.z, a4.w};
            float bv[4] = {b4.x, b4.y, b4.z, b4.w};
#pragma unroll
            for (int i = 0; i < 4; i++)
#pragma unroll
                for (int j = 0; j < 4; j++) acc[i][j] += av[i] * bv[j];
        }
        __syncthreads();
    }

#pragma unroll
    for (int i = 0; i < 4; i++) {
        int gm = m0 + ty * 4 + i;
        if (gm >= M) continue;
#pragma unroll
        for (int j = 0; j < 4; j++) {
            int gn = n0 + tx * 4 + j;
            float v = acc[i][j];
            if (bias) v += bias[gn];
            C[(long)gm * Nc + gn] = v;
        }
    }
}

// ---------------- CSR build ----------------
__global__ __launch_bounds__(256) void hist_kernel(const int* __restrict__ ei,
                                                   int* __restrict__ deg) {
    int e = blockIdx.x * 256 + threadIdx.x;
    if (e >= ETOT) return;
    int d = (e < E_EDGES) ? ei[E_EDGES + e] : e - E_EDGES;
    atomicAdd(&deg[d], 1);
}

__global__ __launch_bounds__(SCAN_BLK) void scan_phase1(const int* __restrict__ deg,
                                                        int* __restrict__ rs,
                                                        int* __restrict__ partials,
                                                        int n) {
    __shared__ int tmp[SCAN_BLK];
    int i = blockIdx.x * SCAN_BLK + threadIdx.x;
    int v = (i < n) ? deg[i] : 0;
    tmp[threadIdx.x] = v;
    __syncthreads();
    for (int off = 1; off < SCAN_BLK; off <<= 1) {
        int t = (threadIdx.x >= (unsigned)off) ? tmp[threadIdx.x - off] : 0;
        __syncthreads();
        tmp[threadIdx.x] += t;
        __syncthreads();
    }
    if (i < n) rs[i] = tmp[threadIdx.x];
    if (threadIdx.x == SCAN_BLK - 1) partials[blockIdx.x] = tmp[SCAN_BLK - 1];
}

__global__ void scan_phase2(int* __restrict__ partials, int nb) {
    if (blockIdx.x == 0 && threadIdx.x == 0) {
        int s = 0;
        for (int i = 0; i < nb; i++) { s += partials[i]; partials[i] = s; }
    }
}

__global__ __launch_bounds__(SCAN_BLK) void scan_phase3(const int* __restrict__ deg,
                                                        int* __restrict__ rs,
                                                        const int* __restrict__ partials,
                                                        int n) {
    int i = blockIdx.x * SCAN_BLK + threadIdx.x;
    if (i < n) {
        int off = (blockIdx.x > 0) ? partials[blockIdx.x - 1] : 0;
        rs[i] = rs[i] + off - deg[i];
    } else if (i == n) {
        rs[n] = partials[gridDim.x - 1];
    }
}

// store SRC node id directly in CSR order (removes one indirection in agg)
__global__ __launch_bounds__(256) void fill_kernel(const int* __restrict__ ei,
                                                   int* __restrict__ cursor,
                                                   int* __restrict__ csr_src) {
    int e = blockIdx.x * 256 + threadIdx.x;
    if (e >= ETOT) return;
    int s, d;
    if (e < E_EDGES) { s = ei[e]; d = ei[E_EDGES + e]; }
    else             { s = d = e - E_EDGES; }
    int pos = atomicAdd(&cursor[d], 1);
    csr_src[pos] = s;
}

// ---------------- CSR gather-aggregate (bf16 xh), fused softmax+bias+relu ----------------
// block = dst node, 128 threads; each thread owns 2 channels via bf16x2.
__global__ __launch_bounds__(128) void agg_kernel(const int* __restrict__ rs,
                                                  const int* __restrict__ csr_src,
                                                  const __hip_bfloat16* __restrict__ xh,
                                                  const float* __restrict__ as_,
                                                  const float* __restrict__ ad_,
                                                  const float* __restrict__ bias,
                                                  float* __restrict__ out) {
    int n = blockIdx.x;
    int c = threadIdx.x;          // pair index: channels 2c, 2c+1
    int h = c >> 5;               // (2c)>>6
    int beg = rs[n], end = rs[n + 1];
    float adv = ad_[n * HEADS + h];
    float acc0 = 0.f, acc1 = 0.f, wsum = 0.f;
    const __hip_bfloat162* xh2 = (const __hip_bfloat162*)xh;
#pragma unroll 4
    for (int p = beg; p < end; ++p) {
        int s = csr_src[p];
        float l = as_[s * HEADS + h] + adv;
        l = l > 0.f ? l : NEG_SLOPE * l;
        float wv = __expf(l);
        wsum += wv;
        __hip_bfloat162 v2 = xh2[(long)s * (HC / 2) + c];
        acc0 += wv * __bfloat162float(v2.x);
        acc1 += wv * __bfloat162float(v2.y);
    }
    float inv = 1.f / (wsum + 1e-16f);
    float o0 = fmaxf(acc0 * inv + bias[2 * c],     0.f);
    float o1 = fmaxf(acc1 * inv + bias[2 * c + 1], 0.f);
    *(float2*)&out[(long)n * HC + 2 * c] = make_float2(o0, o1);
}

extern "C" void kernel_launch(void* const* d_in, const int* in_sizes, int n_in,
                              void* d_out, int out_size, void* d_ws, size_t ws_size,
                              hipStream_t stream) {
    const float* x    = (const float*)d_in[0];
    const int*   ei   = (const int*)d_in[1];
    const float* W1   = (const float*)d_in[3];
    const float* a_s1 = (const float*)d_in[4];
    const float* a_d1 = (const float*)d_in[5];
    const float* b1   = (const float*)d_in[6];
    const float* W2   = (const float*)d_in[7];
    const float* a_s2 = (const float*)d_in[8];
    const float* a_d2 = (const float*)d_in[9];
    const float* b2   = (const float*)d_in[10];
    const float* Wfc  = (const float*)d_in[11];
    const float* bfc  = (const float*)d_in[12];
    float* out = (float*)d_out;

    char* ws = (char*)d_ws;
    size_t off = 0;
    __hip_bfloat16* xh = (__hip_bfloat16*)(ws + off); off += (size_t)N_NODES * HC * 2;  // 25.6MB
    float* bufB    = (float*)(ws + off); off += (size_t)N_NODES * HC * 4;               // 51.2MB
    float* asb     = (float*)(ws + off); off += (size_t)N_NODES * HEADS * 4;
    float* adb     = (float*)(ws + off); off += (size_t)N_NODES * HEADS * 4;
    int*   deg     = (int*)(ws + off);   off += (size_t)N_NODES * 4;
    int*   rs      = (int*)(ws + off);   off += (size_t)(N_NODES + 1) * 4;
    int*   cursor  = (int*)(ws + off);   off += (size_t)N_NODES * 4;
    int*   partials= (int*)(ws + off);   off += 256 * 4;
    int*   csr_src = (int*)(ws + off);   off += (size_t)ETOT * 4;

    dim3 gemm_grid1((N_NODES + 63) / 64, HEADS);
    dim3 gemm_grid_fc((N_NODES + 63) / 64, OUT_DIM / 64);
    int edge_blocks  = (ETOT + 255) / 256;
    int scan_blocks  = (N_NODES + SCAN_BLK - 1) / SCAN_BLK;
    int scan_blocks3 = (N_NODES + 1 + SCAN_BLK - 1) / SCAN_BLK;

    // ---------- CSR build (shared by both layers) ----------
    hipMemsetAsync(deg, 0, (size_t)N_NODES * 4, stream);
    hist_kernel<<<edge_blocks, 256, 0, stream>>>(ei, deg);
    scan_phase1<<<scan_blocks, SCAN_BLK, 0, stream>>>(deg, rs, partials, N_NODES);
    scan_phase2<<<1, 64, 0, stream>>>(partials, scan_blocks);
    scan_phase3<<<scan_blocks3, SCAN_BLK, 0, stream>>>(deg, rs, partials, N_NODES);
    hipMemcpyAsync(cursor, rs, (size_t)N_NODES * 4, hipMemcpyDeviceToDevice, stream);
    fill_kernel<<<edge_blocks, 256, 0, stream>>>(ei, cursor, csr_src);

    // ---------- layer 1 ----------
    gemm_xh<<<gemm_grid1, 256, 0, stream>>>(x, W1, xh, N_NODES, IN_DIM, a_s1, a_d1, asb, adb);
    agg_kernel<<<N_NODES, 128, 0, stream>>>(rs, csr_src, xh, asb, adb, b1, bufB);

    // ---------- layer 2 ----------
    gemm_xh<<<gemm_grid1, 256, 0, stream>>>(bufB, W2, xh, N_NODES, HC, a_s2, a_d2, asb, adb);
    agg_kernel<<<N_NODES, 128, 0, stream>>>(rs, csr_src, xh, asb, adb, b2, bufB);

    // ---------- fc head ----------
    gemm64<<<gemm_grid_fc, 256, 0, stream>>>(bufB, Wfc, out, N_NODES, HC, OUT_DIM, bfc);
}

// Round 5
// 440.249 us; speedup vs baseline: 4.2823x; 1.2456x over previous
//
#include <hip/hip_runtime.h>
#include <hip/hip_bf16.h>

#define N_NODES 50000
#define E_EDGES 800000
#define ETOT (E_EDGES + N_NODES)   // self-loops appended
#define IN_DIM 128
#define HID 64
#define HEADS 4
#define HC (HEADS * HID)           // 256
#define OUT_DIM 64
#define NEG_SLOPE 0.2f
#define SCAN_BLK 1024

using bf16x8 = __attribute__((ext_vector_type(8))) __bf16;
using f32x4  = __attribute__((ext_vector_type(4))) float;

// ---------------- fp32 -> bf16 convert (x) ----------------
__global__ __launch_bounds__(256) void cvt_bf16(const float* __restrict__ in,
                                                __hip_bfloat16* __restrict__ out,
                                                long n4) {   // n4 = n/4
    long i = (long)blockIdx.x * 256 + threadIdx.x;
    if (i >= n4) return;
    float4 v = ((const float4*)in)[i];
    __hip_bfloat162 a, b;
    a.x = __float2bfloat16(v.x); a.y = __float2bfloat16(v.y);
    b.x = __float2bfloat16(v.z); b.y = __float2bfloat16(v.w);
    ((__hip_bfloat162*)out)[2 * i]     = a;
    ((__hip_bfloat162*)out)[2 * i + 1] = b;
}

// ---------------- weight: W[K][N] fp32 -> Wt[N][K] bf16 ----------------
__global__ __launch_bounds__(256) void wtrans(const float* __restrict__ W,
                                              __hip_bfloat16* __restrict__ Wt,
                                              int K, int N) {
    int i = blockIdx.x * 256 + threadIdx.x;
    if (i >= K * N) return;
    int k = i / N, n = i - k * N;
    Wt[(long)n * K + k] = __float2bfloat16(W[i]);
}

// ---------------- MFMA GEMM + fused alphas ----------------
// C[M][256] = A[M][K](bf16) @ B[K][256](bf16, given transposed Bt[256][K]).
// Block: 256 thr = 4 waves; BM=64; wave h owns head h's 64 cols.
// Epilogue: bf16 C store + exact fp32 alpha dots (as_/ad_).
template <int K>
__global__ __launch_bounds__(256) void gemm_xh_mfma(const __hip_bfloat16* __restrict__ A,
                                                    const __hip_bfloat16* __restrict__ Bt,
                                                    __hip_bfloat16* __restrict__ Cb,
                                                    int M,
                                                    const float* __restrict__ a_src,
                                                    const float* __restrict__ a_dst,
                                                    float* __restrict__ as_,
                                                    float* __restrict__ ad_) {
    __shared__ unsigned short Atile[64][K + 8];
    const int t = threadIdx.x;
    const int h = t >> 6;          // wave = head
    const int lane = t & 63;
    const int l15 = lane & 15, l4 = lane >> 4;
    const int m0 = blockIdx.x * 64;

    // ---- stage A tile (64 x K bf16) ----
    constexpr int KB8 = K / 8;     // 16B chunks per row
#pragma unroll
    for (int i = 0; i < K / 32; i++) {        // 64*K/8/256 = K/32 chunks/thread
        int q = i * 256 + t;
        int row = q / KB8;
        int kc = (q - row * KB8) * 8;
        int gm = m0 + row;
        uint4 v = make_uint4(0, 0, 0, 0);
        if (gm < M) v = *(const uint4*)(A + (long)gm * K + kc);
        *(uint4*)&Atile[row][kc] = v;
    }
    __syncthreads();

    f32x4 acc[4][4];               // [rb][cb]
#pragma unroll
    for (int i = 0; i < 4; i++)
#pragma unroll
        for (int j = 0; j < 4; j++) acc[i][j] = (f32x4)0.f;

    const __hip_bfloat16* Bp = Bt + ((long)(h * 64 + l15)) * K + l4 * 8;

#pragma unroll
    for (int kb = 0; kb < K / 32; kb++) {
        bf16x8 bfr[4];
#pragma unroll
        for (int cb = 0; cb < 4; cb++)
            bfr[cb] = *(const bf16x8*)(Bp + (long)cb * 16 * K + kb * 32);
        bf16x8 afr[4];
#pragma unroll
        for (int rb = 0; rb < 4; rb++)
            afr[rb] = *(const bf16x8*)&Atile[rb * 16 + l15][kb * 32 + l4 * 8];
#pragma unroll
        for (int rb = 0; rb < 4; rb++)
#pragma unroll
            for (int cb = 0; cb < 4; cb++)
                acc[rb][cb] = __builtin_amdgcn_mfma_f32_16x16x32_bf16(afr[rb], bfr[cb], acc[rb][cb], 0, 0, 0);
    }

    // ---- epilogue ----
    float asv[4], adv[4];
#pragma unroll
    for (int cb = 0; cb < 4; cb++) {
        asv[cb] = a_src[h * HID + cb * 16 + l15];
        adv[cb] = a_dst[h * HID + cb * 16 + l15];
    }
#pragma unroll
    for (int rb = 0; rb < 4; rb++) {
#pragma unroll
        for (int reg = 0; reg < 4; reg++) {
            int row = m0 + rb * 16 + l4 * 4 + reg;
            float ps = 0.f, pd = 0.f;
#pragma unroll
            for (int cb = 0; cb < 4; cb++) {
                ps += acc[rb][cb][reg] * asv[cb];
                pd += acc[rb][cb][reg] * adv[cb];
            }
#pragma unroll
            for (int off = 8; off; off >>= 1) {
                ps += __shfl_down(ps, off);
                pd += __shfl_down(pd, off);
            }
            if (l15 == 0 && row < M) {
                as_[row * HEADS + h] = ps;
                ad_[row * HEADS + h] = pd;
            }
        }
    }
#pragma unroll
    for (int rb = 0; rb < 4; rb++) {
#pragma unroll
        for (int cb = 0; cb < 4; cb++) {
#pragma unroll
            for (int reg = 0; reg < 4; reg++) {
                int row = m0 + rb * 16 + l4 * 4 + reg;
                int col = h * 64 + cb * 16 + l15;
                if (row < M) Cb[(long)row * HC + col] = __float2bfloat16(acc[rb][cb][reg]);
            }
        }
    }
}

// ---------------- MFMA FC: out[M][64] = A[M][256](bf16) @ Wfct + bias ----------------
__global__ __launch_bounds__(256) void gemm_fc_mfma(const __hip_bfloat16* __restrict__ A,
                                                    const __hip_bfloat16* __restrict__ Bt,  // [64][256]
                                                    const float* __restrict__ bias,
                                                    float* __restrict__ C,
                                                    int M) {
    constexpr int K = 256;
    __shared__ unsigned short Atile[64][K + 8];
    const int t = threadIdx.x;
    const int w = t >> 6;
    const int lane = t & 63;
    const int l15 = lane & 15, l4 = lane >> 4;
    const int m0 = blockIdx.x * 64;

    constexpr int KB8 = K / 8;
#pragma unroll
    for (int i = 0; i < K / 32; i++) {
        int q = i * 256 + t;
        int row = q / KB8;
        int kc = (q - row * KB8) * 8;
        int gm = m0 + row;
        uint4 v = make_uint4(0, 0, 0, 0);
        if (gm < M) v = *(const uint4*)(A + (long)gm * K + kc);
        *(uint4*)&Atile[row][kc] = v;
    }
    __syncthreads();

    f32x4 acc[4];   // [cb], rows w*16..w*16+15
#pragma unroll
    for (int j = 0; j < 4; j++) acc[j] = (f32x4)0.f;

    const __hip_bfloat16* Bp = Bt + (long)l15 * K + l4 * 8;
#pragma unroll
    for (int kb = 0; kb < K / 32; kb++) {
        bf16x8 afr = *(const bf16x8*)&Atile[w * 16 + l15][kb * 32 + l4 * 8];
#pragma unroll
        for (int cb = 0; cb < 4; cb++) {
            bf16x8 bfr = *(const bf16x8*)(Bp + (long)cb * 16 * K + kb * 32);
            acc[cb] = __builtin_amdgcn_mfma_f32_16x16x32_bf16(afr, bfr, acc[cb], 0, 0, 0);
        }
    }
#pragma unroll
    for (int cb = 0; cb < 4; cb++) {
#pragma unroll
        for (int reg = 0; reg < 4; reg++) {
            int row = m0 + w * 16 + l4 * 4 + reg;
            int col = cb * 16 + l15;
            if (row < M) C[(long)row * OUT_DIM + col] = acc[cb][reg] + bias[col];
        }
    }
}

// ---------------- CSR build ----------------
__global__ __launch_bounds__(256) void hist_kernel(const int* __restrict__ ei,
                                                   int* __restrict__ deg) {
    int e = blockIdx.x * 256 + threadIdx.x;
    if (e >= ETOT) return;
    int d = (e < E_EDGES) ? ei[E_EDGES + e] : e - E_EDGES;
    atomicAdd(&deg[d], 1);
}

__global__ __launch_bounds__(SCAN_BLK) void scan_phase1(const int* __restrict__ deg,
                                                        int* __restrict__ rs,
                                                        int* __restrict__ partials,
                                                        int n) {
    __shared__ int tmp[SCAN_BLK];
    int i = blockIdx.x * SCAN_BLK + threadIdx.x;
    int v = (i < n) ? deg[i] : 0;
    tmp[threadIdx.x] = v;
    __syncthreads();
    for (int off = 1; off < SCAN_BLK; off <<= 1) {
        int t = (threadIdx.x >= (unsigned)off) ? tmp[threadIdx.x - off] : 0;
        __syncthreads();
        tmp[threadIdx.x] += t;
        __syncthreads();
    }
    if (i < n) rs[i] = tmp[threadIdx.x];
    if (threadIdx.x == SCAN_BLK - 1) partials[blockIdx.x] = tmp[SCAN_BLK - 1];
}

__global__ void scan_phase2(int* __restrict__ partials, int nb) {
    if (blockIdx.x == 0 && threadIdx.x == 0) {
        int s = 0;
        for (int i = 0; i < nb; i++) { s += partials[i]; partials[i] = s; }
    }
}

__global__ __launch_bounds__(SCAN_BLK) void scan_phase3(const int* __restrict__ deg,
                                                        int* __restrict__ rs,
                                                        const int* __restrict__ partials,
                                                        int n) {
    int i = blockIdx.x * SCAN_BLK + threadIdx.x;
    if (i < n) {
        int off = (blockIdx.x > 0) ? partials[blockIdx.x - 1] : 0;
        rs[i] = rs[i] + off - deg[i];
    } else if (i == n) {
        rs[n] = partials[gridDim.x - 1];
    }
}

__global__ __launch_bounds__(256) void fill_kernel(const int* __restrict__ ei,
                                                   int* __restrict__ cursor,
                                                   int* __restrict__ csr_src) {
    int e = blockIdx.x * 256 + threadIdx.x;
    if (e >= ETOT) return;
    int s, d;
    if (e < E_EDGES) { s = ei[e]; d = ei[E_EDGES + e]; }
    else             { s = d = e - E_EDGES; }
    int pos = atomicAdd(&cursor[d], 1);
    csr_src[pos] = s;
}

// ---------------- CSR gather-aggregate (bf16 in/out), fused softmax+bias+relu ----------------
__global__ __launch_bounds__(128) void agg_kernel(const int* __restrict__ rs,
                                                  const int* __restrict__ csr_src,
                                                  const __hip_bfloat16* __restrict__ xh,
                                                  const float* __restrict__ as_,
                                                  const float* __restrict__ ad_,
                                                  const float* __restrict__ bias,
                                                  __hip_bfloat16* __restrict__ out) {
    int n = blockIdx.x;
    int c = threadIdx.x;          // pair index: channels 2c, 2c+1
    int h = c >> 5;
    int beg = rs[n], end = rs[n + 1];
    float adv = ad_[n * HEADS + h];
    float acc0 = 0.f, acc1 = 0.f, wsum = 0.f;
    const __hip_bfloat162* xh2 = (const __hip_bfloat162*)xh;
#pragma unroll 4
    for (int p = beg; p < end; ++p) {
        int s = csr_src[p];
        float l = as_[s * HEADS + h] + adv;
        l = l > 0.f ? l : NEG_SLOPE * l;
        float wv = __expf(l);
        wsum += wv;
        __hip_bfloat162 v2 = xh2[(long)s * (HC / 2) + c];
        acc0 += wv * __bfloat162float(v2.x);
        acc1 += wv * __bfloat162float(v2.y);
    }
    float inv = 1.f / (wsum + 1e-16f);
    __hip_bfloat162 o;
    o.x = __float2bfloat16(fmaxf(acc0 * inv + bias[2 * c],     0.f));
    o.y = __float2bfloat16(fmaxf(acc1 * inv + bias[2 * c + 1], 0.f));
    *(__hip_bfloat162*)&out[(long)n * HC + 2 * c] = o;
}

extern "C" void kernel_launch(void* const* d_in, const int* in_sizes, int n_in,
                              void* d_out, int out_size, void* d_ws, size_t ws_size,
                              hipStream_t stream) {
    const float* x    = (const float*)d_in[0];
    const int*   ei   = (const int*)d_in[1];
    const float* W1   = (const float*)d_in[3];
    const float* a_s1 = (const float*)d_in[4];
    const float* a_d1 = (const float*)d_in[5];
    const float* b1   = (const float*)d_in[6];
    const float* W2   = (const float*)d_in[7];
    const float* a_s2 = (const float*)d_in[8];
    const float* a_d2 = (const float*)d_in[9];
    const float* b2   = (const float*)d_in[10];
    const float* Wfc  = (const float*)d_in[11];
    const float* bfc  = (const float*)d_in[12];
    float* out = (float*)d_out;

    char* ws = (char*)d_ws;
    size_t off = 0;
    __hip_bfloat16* xb  = (__hip_bfloat16*)(ws + off); off += (size_t)N_NODES * IN_DIM * 2;  // 12.8MB
    __hip_bfloat16* xh  = (__hip_bfloat16*)(ws + off); off += (size_t)N_NODES * HC * 2;      // 25.6MB
    __hip_bfloat16* y   = (__hip_bfloat16*)(ws + off); off += (size_t)N_NODES * HC * 2;      // 25.6MB
    __hip_bfloat16* W1t = (__hip_bfloat16*)(ws + off); off += (size_t)HC * IN_DIM * 2;
    __hip_bfloat16* W2t = (__hip_bfloat16*)(ws + off); off += (size_t)HC * HC * 2;
    __hip_bfloat16* Wft = (__hip_bfloat16*)(ws + off); off += (size_t)OUT_DIM * HC * 2;
    float* asb     = (float*)(ws + off); off += (size_t)N_NODES * HEADS * 4;
    float* adb     = (float*)(ws + off); off += (size_t)N_NODES * HEADS * 4;
    int*   deg     = (int*)(ws + off);   off += (size_t)N_NODES * 4;
    int*   rs      = (int*)(ws + off);   off += (size_t)(N_NODES + 1) * 4;
    int*   cursor  = (int*)(ws + off);   off += (size_t)N_NODES * 4;
    int*   partials= (int*)(ws + off);   off += 256 * 4;
    int*   csr_src = (int*)(ws + off);   off += (size_t)ETOT * 4;

    int mblocks = (N_NODES + 63) / 64;
    int edge_blocks  = (ETOT + 255) / 256;
    int scan_blocks  = (N_NODES + SCAN_BLK - 1) / SCAN_BLK;
    int scan_blocks3 = (N_NODES + 1 + SCAN_BLK - 1) / SCAN_BLK;

    // ---------- converts ----------
    long x4 = (long)N_NODES * IN_DIM / 4;
    cvt_bf16<<<(int)((x4 + 255) / 256), 256, 0, stream>>>(x, xb, x4);
    wtrans<<<(IN_DIM * HC + 255) / 256, 256, 0, stream>>>(W1, W1t, IN_DIM, HC);
    wtrans<<<(HC * HC + 255) / 256, 256, 0, stream>>>(W2, W2t, HC, HC);
    wtrans<<<(HC * OUT_DIM + 255) / 256, 256, 0, stream>>>(Wfc, Wft, HC, OUT_DIM);

    // ---------- CSR build (shared by both layers) ----------
    hipMemsetAsync(deg, 0, (size_t)N_NODES * 4, stream);
    hist_kernel<<<edge_blocks, 256, 0, stream>>>(ei, deg);
    scan_phase1<<<scan_blocks, SCAN_BLK, 0, stream>>>(deg, rs, partials, N_NODES);
    scan_phase2<<<1, 64, 0, stream>>>(partials, scan_blocks);
    scan_phase3<<<scan_blocks3, SCAN_BLK, 0, stream>>>(deg, rs, partials, N_NODES);
    hipMemcpyAsync(cursor, rs, (size_t)N_NODES * 4, hipMemcpyDeviceToDevice, stream);
    fill_kernel<<<edge_blocks, 256, 0, stream>>>(ei, cursor, csr_src);

    // ---------- layer 1 ----------
    gemm_xh_mfma<IN_DIM><<<mblocks, 256, 0, stream>>>(xb, W1t, xh, N_NODES, a_s1, a_d1, asb, adb);
    agg_kernel<<<N_NODES, 128, 0, stream>>>(rs, csr_src, xh, asb, adb, b1, y);

    // ---------- layer 2 ----------
    gemm_xh_mfma<HC><<<mblocks, 256, 0, stream>>>(y, W2t, xh, N_NODES, a_s2, a_d2, asb, adb);
    agg_kernel<<<N_NODES, 128, 0, stream>>>(rs, csr_src, xh, asb, adb, b2, y);

    // ---------- fc head ----------
    gemm_fc_mfma<<<mblocks, 256, 0, stream>>>(y, Wft, bfc, out, N_NODES);
}